// Round 2
// baseline (641.640 us; speedup 1.0000x reference)
//
#include <hip/hip_runtime.h>
#include <math.h>

// NM-LSTM step, B=256, IN=HS=512, NM=1, fp32 — SINGLE fused kernel.
// d_out layout: h_new (256*512) | c_new (256*512) | hebb_new (256*512*512)
//
// Round-2 change: gates_gemm folded into the hebb kernel as a per-block GEMV
// (each (b,jt) block computes its own 4x32 gate columns from L2-resident W/U
// strips, overlapped with the 64KB hebb slab HBM loads). Gates never touch
// DRAM; one dispatch instead of two.

__device__ __forceinline__ float sigm(float x) { return 1.0f / (1.0f + __expf(-x)); }
__device__ __forceinline__ float tanh_fast(float x) { return 1.0f - 2.0f / (1.0f + __expf(2.0f * x)); }
__device__ __forceinline__ float clip2(float v) { return fminf(fmaxf(v, -2.0f), 2.0f); }

// Grid: 4096 = 16 jt-tiles (MAJOR: same-jt blocks consecutive -> the 512KB
// W/U column strip stays hot in each XCD's L2) x 256 batch rows.
// Block: 512 threads; thread t: tj4 = t&7 (float4 col), ti = t>>3 (8 rows).
// Hebb slab per block: 512x32 fp32 = 64KB in r[8] float4 (32 VGPR, pinned).
// __launch_bounds__(512,6): 3 blocks/CU, <=84 VGPR — headroom so the pinned
// slab + GEMV in-flight loads cannot spill (round 1 showed occupancy beyond
// 2 blocks/CU buys nothing, so trading occupancy for register safety).
__global__ __launch_bounds__(512, 6)
void nm_lstm_fused(const float* __restrict__ x_t, const float* __restrict__ h_t,
                   const float* __restrict__ c_t, const float* __restrict__ hebb,
                   const float* __restrict__ W, const float* __restrict__ U,
                   const float* __restrict__ bias, const float* __restrict__ alpha,
                   const float* __restrict__ nm_w, const float* __restrict__ nm_b,
                   const float* __restrict__ mt_w, const float* __restrict__ mt_b,
                   float* __restrict__ out)
{
    const int bx = blockIdx.x;
    const int jt = bx >> 8;      // 0..15 (jt-major)
    const int b  = bx & 255;
    const int t  = threadIdx.x;
    const int tj4 = t & 7;       // float4 column group within 32-col tile
    const int ti  = t >> 3;      // row group (8 rows each), 0..63

    __shared__ __align__(16) float xh[1024];        // [x[b,:] | h[b,:]]
    __shared__ float redm[512];                     // m_t partials
    __shared__ __align__(16) float red[64][36];     // hebb column partials (pitch 36)
    __shared__ float gred[4][128];                  // GEMV k-chunk partials
    __shared__ float gsh[128];                      // finished gate pre-activations
    __shared__ __align__(16) float upd[32];
    __shared__ float msh;

    // --- hebb slab loads FIRST (longest-latency HBM stream; 8 dwordx4) ---
    const float4* hb    = (const float4*)(hebb + (size_t)b * 262144);
    const int     cbase = jt * 8 + tj4;             // float4 col, row pitch 128
    float4 r[8];
    #pragma unroll
    for (int k = 0; k < 8; ++k)
        r[k] = hb[(size_t)(ti * 8 + k) * 128 + cbase];

    // --- stage [x|h] + m_t partials ---
    const float xv  = x_t[(size_t)b * 512 + t];
    const float hv0 = h_t[(size_t)b * 512 + t];
    xh[t]       = xv;
    xh[512 + t] = hv0;
    redm[t]     = hv0 * nm_w[t];
    __syncthreads();

    // --- gates GEMV, overlapped with slab-load drain ---
    // 128 outputs (4 gates x 32 cols) x 4 k-chunks of 256. q uniform per wave
    // -> xh reads are LDS broadcasts; 32 consecutive lanes read 128B-coalesced
    // W/U line segments (L2-resident strip).
    const int o    = t & 127;                       // gate = o>>5, col = o&31
    const int q    = t >> 7;                        // k-chunk 0..3
    const int gcol = (o >> 5) * 512 + jt * 32 + (o & 31);
    const float* Bp = (q < 2) ? (W + (size_t)(q * 256) * 2048 + gcol)
                              : (U + (size_t)((q - 2) * 256) * 2048 + gcol);
    const float* xp = &xh[q * 256];
    float acc = 0.f;
    #pragma unroll 4
    for (int k = 0; k < 256; ++k)
        acc += xp[k] * Bp[(size_t)k * 2048];
    gred[q][o] = acc;

    // --- m_t reduction on wave 0 ---
    if (t < 64) {
        float v = 0.f;
        #pragma unroll
        for (int qq = 0; qq < 8; ++qq) v += redm[t + qq * 64];
        #pragma unroll
        for (int off = 32; off > 0; off >>= 1) v += __shfl_down(v, off);
        if (t == 0) msh = tanh_fast(v + nm_b[0]);
    }
    __syncthreads();

    // --- gates finalize: 128 threads sum 4 chunk-partials + bias -> gsh ---
    if (t < 128) {
        const int gc = (t >> 5) * 512 + jt * 32 + (t & 31);
        gsh[t] = gred[0][t] + gred[1][t] + gred[2][t] + gred[3][t] + bias[gc];
    }

    // --- hebb column partial sums over this thread's 8 rows ---
    float4 ps = {0.f, 0.f, 0.f, 0.f};
    #pragma unroll
    for (int k = 0; k < 8; ++k) {
        const float hv = xh[512 + ti * 8 + k];
        ps.x += hv * r[k].x;
        ps.y += hv * r[k].y;
        ps.z += hv * r[k].z;
        ps.w += hv * r[k].w;
    }
    *(float4*)&red[ti][tj4 * 4] = ps;
    __syncthreads();   // red + gsh + msh all visible

    // --- finalize on wave 0: halves sum 32 row-groups each, combine,
    //     then LSTM epilogue on lanes 0-31 (gates read from LDS, not DRAM) ---
    if (t < 64) {
        const int c  = t & 31;
        const int hf = t >> 5;
        float s = 0.f;
        #pragma unroll
        for (int qq = 0; qq < 32; ++qq) s += red[hf * 32 + qq][c];
        s += __shfl_xor(s, 32);
        if (hf == 0) {
            const int j = jt * 32 + c;
            const float g  = tanh_fast(gsh[64 + c] + alpha[j] * s);
            const float mm = msh * mt_w[j] + mt_b[j];
            upd[c] = mm * g;
            const float it_ = sigm(gsh[c]);
            const float ft  = sigm(gsh[32 + c]);
            const float ot  = sigm(gsh[96 + c]);
            const float cn  = ft * c_t[(size_t)b * 512 + j] + it_ * g;
            out[(size_t)b * 512 + j]          = ot * tanh_fast(cn);   // h_new
            out[131072 + (size_t)b * 512 + j] = cn;                   // c_new
        }
    }
    __syncthreads();

    // --- hebb update + clip + store ---
    const float4 u = *(const float4*)&upd[tj4 * 4];
    float4* ho = (float4*)(out + 262144 + (size_t)b * 262144);
    #pragma unroll
    for (int k = 0; k < 8; ++k) {
        const float hv = xh[512 + ti * 8 + k];
        float4 w;
        w.x = clip2(r[k].x + u.x * hv);
        w.y = clip2(r[k].y + u.y * hv);
        w.z = clip2(r[k].z + u.z * hv);
        w.w = clip2(r[k].w + u.w * hv);
        ho[(size_t)(ti * 8 + k) * 128 + cbase] = w;
    }
}

extern "C" void kernel_launch(void* const* d_in, const int* in_sizes, int n_in,
                              void* d_out, int out_size, void* d_ws, size_t ws_size,
                              hipStream_t stream)
{
    const float* x_t   = (const float*)d_in[0];
    const float* h_t   = (const float*)d_in[1];
    const float* c_t   = (const float*)d_in[2];
    const float* hebb  = (const float*)d_in[3];
    const float* W     = (const float*)d_in[4];
    const float* U     = (const float*)d_in[5];
    const float* bias  = (const float*)d_in[6];
    const float* alpha = (const float*)d_in[7];
    const float* nm_w  = (const float*)d_in[8];
    const float* nm_b  = (const float*)d_in[9];
    const float* mt_w  = (const float*)d_in[10];
    const float* mt_b  = (const float*)d_in[11];
    float* out = (float*)d_out;

    nm_lstm_fused<<<4096, 512, 0, stream>>>(x_t, h_t, c_t, hebb, W, U, bias,
                                            alpha, nm_w, nm_b, mt_w, mt_b, out);
}

// Round 3
// 507.812 us; speedup vs baseline: 1.2635x; 1.2635x over previous
//
#include <hip/hip_runtime.h>
#include <math.h>

// NM-LSTM step, B=256, IN=HS=512, NM=1, fp32.
// d_out layout: h_new (256*512) | c_new (256*512) | hebb_new (256*512*512)
//
// Round-3: revert round-2 GEMV fusion (measured 309 us @ 1.4 TB/s — L2
// GEMV latency-bound on the critical path). Back to two kernels; hebb
// restructured as persistent 4-tile blocks with double-buffered register
// slabs so next-tile HBM loads are in flight during reduce/finalize/store.

__device__ __forceinline__ float sigm(float x) { return 1.0f / (1.0f + __expf(-x)); }
__device__ __forceinline__ float tanh_fast(float x) { return 1.0f - 2.0f / (1.0f + __expf(2.0f * x)); }
__device__ __forceinline__ float clip2(float v) { return fminf(fmaxf(v, -2.0f), 2.0f); }

// ---------------------------------------------------------------------------
// Kernel 1: raw gates = [x|h] @ [W;U] + bias -> ws (256 x 2048), fp32.
// Byte-identical to round 0/1 (measured ~25-30 us; not the bottleneck).
// ---------------------------------------------------------------------------
__global__ __launch_bounds__(256, 4)
void gates_gemm(const float* __restrict__ x, const float* __restrict__ h,
                const float* __restrict__ W, const float* __restrict__ U,
                const float* __restrict__ bias, float* __restrict__ gates)
{
    __shared__ float As[64][64];   // [k][row]
    __shared__ float Bs[64][40];   // [k][col], padded pitch 40

    const int t     = threadIdx.x;
    const int bcol0 = blockIdx.x * 32;
    const int brow0 = blockIdx.y * 64;
    const int row   = t & 63;
    const int cg    = t >> 6;      // 0..3, 8 cols each

    float acc[8] = {};

    for (int ks = 0; ks < 16; ++ks) {
        const float* srcA;
        const float* srcB;
        int ka;
        if (ks < 8) { srcA = x; srcB = W; ka = ks * 64; }
        else        { srcA = h; srcB = U; ka = ks * 64 - 512; }

        float4 av[4];
        #pragma unroll
        for (int m = 0; m < 4; ++m)
            av[m] = *(const float4*)&srcA[(size_t)(brow0 + row) * 512 + ka + cg * 16 + m * 4];
        const int kr0 = t >> 3;        // 0..31
        const int c4  = t & 7;         // 0..7
        float4 bv0 = *(const float4*)&srcB[(size_t)(ka + kr0)      * 2048 + bcol0 + c4 * 4];
        float4 bv1 = *(const float4*)&srcB[(size_t)(ka + kr0 + 32) * 2048 + bcol0 + c4 * 4];

        __syncthreads();
        #pragma unroll
        for (int m = 0; m < 4; ++m) {
            As[cg * 16 + m * 4 + 0][row] = av[m].x;
            As[cg * 16 + m * 4 + 1][row] = av[m].y;
            As[cg * 16 + m * 4 + 2][row] = av[m].z;
            As[cg * 16 + m * 4 + 3][row] = av[m].w;
        }
        *(float4*)&Bs[kr0][c4 * 4]      = bv0;
        *(float4*)&Bs[kr0 + 32][c4 * 4] = bv1;
        __syncthreads();

        #pragma unroll
        for (int k = 0; k < 64; ++k) {
            const float a = As[k][row];
            const float4 b0 = *(const float4*)&Bs[k][cg * 8];
            const float4 b1 = *(const float4*)&Bs[k][cg * 8 + 4];
            acc[0] += a * b0.x; acc[1] += a * b0.y; acc[2] += a * b0.z; acc[3] += a * b0.w;
            acc[4] += a * b1.x; acc[5] += a * b1.y; acc[6] += a * b1.z; acc[7] += a * b1.w;
        }
    }

    const int colb = bcol0 + cg * 8;
    float4 o0, o1;
    o0.x = acc[0] + bias[colb + 0]; o0.y = acc[1] + bias[colb + 1];
    o0.z = acc[2] + bias[colb + 2]; o0.w = acc[3] + bias[colb + 3];
    o1.x = acc[4] + bias[colb + 4]; o1.y = acc[5] + bias[colb + 5];
    o1.z = acc[6] + bias[colb + 6]; o1.w = acc[7] + bias[colb + 7];
    float* gp = &gates[(size_t)(brow0 + row) * 2048 + colb];
    *(float4*)gp       = o0;
    *(float4*)(gp + 4) = o1;
}

// ---------------------------------------------------------------------------
// Kernel 2: persistent 4-tile hebb blocks, double-buffered register slabs.
// Grid: 1024 blocks = 256 b x 4 tile-groups; block p: b = p>>2,
// j-tiles jt0..jt0+3 with jt0 = (p&3)*4 (128 adjacent columns -> same DRAM
// pages, 1KB-contiguous per row across the block's 4 tiles).
// Per tile: slab 512x32 fp32 = 64KB in 8 float4 regs; two buffers alternate
// so tile i+1's loads are issued before tile i's reduce/finalize/store.
// Mechanism: removes the lockstep load->barrier->compute->store bubbles that
// kept round-1 hebb at ~3.4 TB/s (150 us vs ~90 us roofline).
// b constant per block -> h row staged + m_t reduced ONCE.
// ---------------------------------------------------------------------------
__global__ __launch_bounds__(512, 4)
void hebb_fused(const float* __restrict__ h_t, const float* __restrict__ c_t,
                const float* __restrict__ hebb, const float* __restrict__ alpha,
                const float* __restrict__ nm_w, const float* __restrict__ nm_b,
                const float* __restrict__ mt_w, const float* __restrict__ mt_b,
                const float* __restrict__ gates, float* __restrict__ out)
{
    const int p   = blockIdx.x;        // 0..1023
    const int b   = p >> 2;
    const int jt0 = (p & 3) * 4;       // first of 4 consecutive j-tiles
    const int t   = threadIdx.x;
    const int tj4 = t & 7;             // float4 column within 32-col tile
    const int ti  = t >> 3;            // row group (8 rows), 0..63
    const int rbase = ti * 8;

    __shared__ float hsh[512];
    __shared__ float redm[512];
    __shared__ __align__(16) float red[64][36];   // pitch 36: 2-way banks (free)
    __shared__ __align__(16) float upd[32];
    __shared__ float msh;

    const float4* hb = (const float4*)(hebb + (size_t)b * 262144);
    float4*       ho = (float4*)(out + 262144 + (size_t)b * 262144);

    // --- tile 0 slab loads first (HBM stream starts immediately) ---
    float4 A[8], Bv[8];
    const int cb0 = jt0 * 8 + tj4;
    #pragma unroll
    for (int k = 0; k < 8; ++k)
        A[k] = hb[(size_t)(rbase + k) * 128 + cb0];

    // --- stage h row + m_t partials (once per block) ---
    const float hv0 = h_t[(size_t)b * 512 + t];
    hsh[t]  = hv0;
    redm[t] = hv0 * nm_w[t];
    __syncthreads();

    if (t < 64) {
        float v = 0.f;
        #pragma unroll
        for (int q = 0; q < 8; ++q) v += redm[t + q * 64];
        #pragma unroll
        for (int off = 32; off > 0; off >>= 1) v += __shfl_down(v, off);
        if (t == 0) msh = tanh_fast(v + nm_b[0]);
    }

    // local copy of the 8 h values this thread's rows use (regs, not LDS)
    float hrow[8];
    #pragma unroll
    for (int k = 0; k < 8; ++k) hrow[k] = hsh[rbase + k];

    const size_t gb = (size_t)b * 2048;

    #pragma unroll
    for (int i = 0; i < 4; ++i) {
        float4* cur = (i & 1) ? Bv : A;   // i is compile-time under unroll
        float4* nxt = (i & 1) ? A  : Bv;

        // issue next tile's loads BEFORE consuming current (vmcnt overlap)
        if (i < 3) {
            const int cbn = (jt0 + i + 1) * 8 + tj4;
            #pragma unroll
            for (int k = 0; k < 8; ++k)
                nxt[k] = hb[(size_t)(rbase + k) * 128 + cbn];
        }

        // column partial sums over this thread's 8 rows
        float4 ps = {0.f, 0.f, 0.f, 0.f};
        #pragma unroll
        for (int k = 0; k < 8; ++k) {
            ps.x += hrow[k] * cur[k].x;
            ps.y += hrow[k] * cur[k].y;
            ps.z += hrow[k] * cur[k].z;
            ps.w += hrow[k] * cur[k].w;
        }
        *(float4*)&red[ti][tj4 * 4] = ps;
        __syncthreads();   // red complete (+ msh visible, tile 0)

        // finalize on wave 0: two halves sum 32 row-groups, combine, epilogue
        if (t < 64) {
            const int c  = t & 31;
            const int hf = t >> 5;
            float s = 0.f;
            #pragma unroll
            for (int q = 0; q < 32; ++q) s += red[hf * 32 + q][c];
            s += __shfl_xor(s, 32);
            if (hf == 0) {
                const int j = (jt0 + i) * 32 + c;
                const float g  = tanh_fast(gates[gb + 1024 + j] + alpha[j] * s);
                const float mm = msh * mt_w[j] + mt_b[j];
                upd[c] = mm * g;
                const float it_ = sigm(gates[gb + j]);
                const float ft  = sigm(gates[gb + 512 + j]);
                const float ot  = sigm(gates[gb + 1536 + j]);
                const float cn  = ft * c_t[(size_t)b * 512 + j] + it_ * g;
                out[(size_t)b * 512 + j]          = ot * tanh_fast(cn);   // h_new
                out[131072 + (size_t)b * 512 + j] = cn;                   // c_new
            }
        }
        __syncthreads();   // upd visible; red free for next tile

        // hebb update + clip + store (fire-and-forget; next loads in flight)
        const float4 u  = *(const float4*)&upd[tj4 * 4];
        const int   cbi = (jt0 + i) * 8 + tj4;
        #pragma unroll
        for (int k = 0; k < 8; ++k) {
            float4 w;
            w.x = clip2(cur[k].x + u.x * hrow[k]);
            w.y = clip2(cur[k].y + u.y * hrow[k]);
            w.z = clip2(cur[k].z + u.z * hrow[k]);
            w.w = clip2(cur[k].w + u.w * hrow[k]);
            ho[(size_t)(rbase + k) * 128 + cbi] = w;
        }
    }
}

extern "C" void kernel_launch(void* const* d_in, const int* in_sizes, int n_in,
                              void* d_out, int out_size, void* d_ws, size_t ws_size,
                              hipStream_t stream)
{
    const float* x_t   = (const float*)d_in[0];
    const float* h_t   = (const float*)d_in[1];
    const float* c_t   = (const float*)d_in[2];
    const float* hebb  = (const float*)d_in[3];
    const float* W     = (const float*)d_in[4];
    const float* U     = (const float*)d_in[5];
    const float* bias  = (const float*)d_in[6];
    const float* alpha = (const float*)d_in[7];
    const float* nm_w  = (const float*)d_in[8];
    const float* nm_b  = (const float*)d_in[9];
    const float* mt_w  = (const float*)d_in[10];
    const float* mt_b  = (const float*)d_in[11];
    float* out   = (float*)d_out;
    float* gates = (float*)d_ws;   // 256*2048 fp32 = 2 MB raw gates

    dim3 g1(64, 4);   // 2048/32 col-tiles x 256/64 row-tiles = 256 blocks
    gates_gemm<<<g1, 256, 0, stream>>>(x_t, h_t, W, U, bias, gates);
    hebb_fused<<<1024, 512, 0, stream>>>(h_t, c_t, hebb, alpha, nm_w, nm_b,
                                         mt_w, mt_b, gates, out);
}